// Round 5
// baseline (1742.652 us; speedup 1.0000x reference)
//
#include <hip/hip_runtime.h>
#include <hip/hip_fp16.h>
#include <stdint.h>

typedef _Float16 f16;
typedef _Float16 f16x8 __attribute__((ext_vector_type(8)));
typedef float    f32x4v __attribute__((ext_vector_type(4)));
typedef float    f32x16 __attribute__((ext_vector_type(16)));

#define NEDGE 1000000
#define NT    31250        // 32-edge tiles (31250*32 = 1e6)
#define NTHR  512
#define GRID  256
#define GW    (GRID*8)     // 2048 waves

// ---- d_ws layout (bytes) ----
// Weight frags are 1 KB each (64 lanes x 16 B), sigma-row-permuted (see below).
#define W1OFF 0                 // 64 frags: f = nt*16+ks   (nt 0..3,  ks 0..15)
#define W2OFF 65536             // 64 frags: f = nt*8+ks    (nt 0..7,  ks 0..7)
#define W3OFF 131072            // 32 frags: f = nt*16+ks   (nt 0..1,  ks 0..15)
#define W4OFF 163840            // 4 frags:  f = ks         (ks 0..3)
#define BDOFF 167936            // biasD: 14*2*16 f32 = 1792 B
#define ZUOFF 169984
#define ZBOFF (ZUOFF + 100000*128*2)
#define WS_FULL (ZBOFF + 100000*128*2)

// sigma: swap bits 2<->3 (involution). Producer rows permuted by sigma make the
// MFMA D-register order equal the next layer's B-frag order (lane-local pack).
__device__ __forceinline__ int sw23(int i) {
    return (i & 3) | ((i >> 1) & 4) | ((i << 1) & 8) | (i & 16);
}

// ---------------- weight fragment + biasD builder ----------------
// A-frag (32x32x16 swapped use): lane&31 = row i, k = (lane>>5)*8 + e.
// Rows of W1/W2/W3 frags hold neuron n = nt*32 + sw23(i).
__global__ __launch_bounds__(512) void wfrag_kernel(
    const float* __restrict__ W1, const float* __restrict__ b1,
    const float* __restrict__ W2, const float* __restrict__ b2,
    const float* __restrict__ W3, const float* __restrict__ b3,
    const float* __restrict__ W4, float* __restrict__ wsf)
{
    f16* ws = (f16*)wsf;
    const int NF = 164*64;
    int tid = blockIdx.x*512 + threadIdx.x;
    if (tid < NF) {
        int f = tid >> 6, lane = tid & 63;
        int li = lane & 31, hi = lane >> 5;
        int ip = sw23(li);
        f16 v[8];
        if (f < 64) {                       // W1 [128,256]
            int nt = f >> 4, ks = f & 15, n = nt*32 + ip;
            #pragma unroll
            for (int e = 0; e < 8; ++e) v[e] = (f16)W1[n*256 + ks*16 + hi*8 + e];
        } else if (f < 128) {               // W2 [256,128]
            int g = f-64, nt = g >> 3, ks = g & 7, n = nt*32 + ip;
            #pragma unroll
            for (int e = 0; e < 8; ++e) v[e] = (f16)W2[n*128 + ks*16 + hi*8 + e];
        } else if (f < 160) {               // W3 [64,256]
            int g = f-128, nt = g >> 4, ks = g & 15, n = nt*32 + ip;
            #pragma unroll
            for (int e = 0; e < 8; ++e) v[e] = (f16)W3[n*256 + ks*16 + hi*8 + e];
        } else {                            // W4 [5,64], rows >=5 zero, NO sigma
            int ks = f-160;
            #pragma unroll
            for (int e = 0; e < 8; ++e)
                v[e] = (li < 5) ? (f16)W4[li*64 + ks*16 + hi*8 + e] : (f16)0;
        }
        f16* d = ws + (size_t)f*512 + lane*8;
        #pragma unroll
        for (int e = 0; e < 8; ++e) d[e] = v[e];
    } else if (tid < NF + 448) {
        // biasD[nt14][hi][r] = b[nt*32 + (r&7) + 8*hi + 16*(r>>3)]
        int j = tid - NF;
        int r = j & 15, hi = (j >> 4) & 1, nt = j >> 5;
        int n32 = (r & 7) + 8*hi + 16*(r >> 3);
        float bv = (nt < 4)  ? b1[nt*32 + n32]
                 : (nt < 12) ? b2[(nt-4)*32 + n32]
                             : b3[(nt-12)*32 + n32];
        *(float*)((char*)wsf + BDOFF + j*4) = bv;
    }
}

// ---------------- embedding f32 -> f16 ----------------
__device__ __forceinline__ void cvt8(const float* __restrict__ s, f16* __restrict__ d) {
    float4 a = ((const float4*)s)[0], b = ((const float4*)s)[1];
    union { f16 h[8]; uint4 u; } r;
    r.h[0]=(f16)a.x; r.h[1]=(f16)a.y; r.h[2]=(f16)a.z; r.h[3]=(f16)a.w;
    r.h[4]=(f16)b.x; r.h[5]=(f16)b.y; r.h[6]=(f16)b.z; r.h[7]=(f16)b.w;
    *(uint4*)d = r.u;
}
__global__ __launch_bounds__(512) void ecvt_kernel(
    const float* __restrict__ zu, const float* __restrict__ zb,
    f16* __restrict__ du, f16* __restrict__ db)
{
    const int NPER = 100000*128/8;
    int i = blockIdx.x*512 + threadIdx.x;
    if (i < NPER)          cvt8(zu + (size_t)i*8, du + (size_t)i*8);
    else if (i < 2*NPER) { int j = i - NPER; cvt8(zb + (size_t)j*8, db + (size_t)j*8); }
}

__device__ __forceinline__ unsigned int pkrne(float v0, float v1) {
    union { f16 h[2]; unsigned int u; } r;
    r.h[0] = (f16)v0; r.h[1] = (f16)v1; return r.u;
}

// pure lane-local epilogue (sigma pre-permutation makes this correct):
// frag P element e (lane half hi) = relu(acc reg 8P+e) = neuron 16P + 8hi + e.
template<bool RELU, int P>
__device__ __forceinline__ f16x8 mkfrag(f32x16 a) {
    float v0=a[8*P+0], v1=a[8*P+1], v2=a[8*P+2], v3=a[8*P+3];
    float v4=a[8*P+4], v5=a[8*P+5], v6=a[8*P+6], v7=a[8*P+7];
    if (RELU) {
        v0=fmaxf(v0,0.f); v1=fmaxf(v1,0.f); v2=fmaxf(v2,0.f); v3=fmaxf(v3,0.f);
        v4=fmaxf(v4,0.f); v5=fmaxf(v5,0.f); v6=fmaxf(v6,0.f); v7=fmaxf(v7,0.f);
    }
    union { unsigned int u[4]; f16x8 v; } fb;
    fb.u[0]=pkrne(v0,v1); fb.u[1]=pkrne(v2,v3); fb.u[2]=pkrne(v4,v5); fb.u[3]=pkrne(v6,v7);
    return fb.v;
}

// acc init from biasD (broadcast ds_reads, uniform addr per half-wave)
__device__ __forceinline__ f32x16 bias_init(const float* sB, int nt14, int hi) {
    const f32x4v* p = (const f32x4v*)(sB + (nt14*2 + hi)*16);
    f32x4v q0=p[0], q1=p[1], q2=p[2], q3=p[3];
    f32x16 a;
    a[0]=q0[0];  a[1]=q0[1];  a[2]=q0[2];  a[3]=q0[3];
    a[4]=q1[0];  a[5]=q1[1];  a[6]=q1[2];  a[7]=q1[3];
    a[8]=q2[0];  a[9]=q2[1];  a[10]=q2[2]; a[11]=q2[3];
    a[12]=q3[0]; a[13]=q3[1]; a[14]=q3[2]; a[15]=q3[3];
    return a;
}

#define MFMA(A,B,C) __builtin_amdgcn_mfma_f32_32x32x16_f16((A),(B),(C),0,0,0)
#define LD12(f) (*(const f16x8*)(sW12 + ((f) << 9) + (lane << 3)))
#define LDT3(f) (*(const f16x8*)(sW3t + ((f) << 9) + (lane << 3)))
#define SEL8(k, v0,v1,v2,v3,v4,v5,v6,v7) \
    ((k)==0?(v0):(k)==1?(v1):(k)==2?(v2):(k)==3?(v3): \
     (k)==4?(v4):(k)==5?(v5):(k)==6?(v6):(v7))

// ---------------- fused streaming edge MLP ----------------
// 8 waves/block, 1 block/CU (LDS 157.8 KB). All weights LDS-resident except
// W3 k-tiles 14,15 (4 KB, L2-hot) and W4 (registers). No barriers in loop,
// all inter-layer state lane-local SSA. Zero bias columns (acc-init instead).
template<bool EF16>
__global__ __launch_bounds__(NTHR, 2) void edge_mlp(
    const int* __restrict__ eli,
    const float* __restrict__ zu, const float* __restrict__ zb,
    const f16* __restrict__ zu16, const f16* __restrict__ zb16,
    const f16* __restrict__ wsw, const float* __restrict__ b4,
    float* __restrict__ out)
{
    __shared__ f16 sW12[128*512];    // 131072 B : W1 frags 0..63, W2 frags 64..127
    __shared__ f16 sW3t[28*512];     // 28672 B  : W3 frags nt*14+ks, ks<14
    __shared__ float sBias[448];     // 1792 B

    const int tid = threadIdx.x;
    const int lane = tid & 63;
    const int li = lane & 31;
    const int hi = lane >> 5;

    // ---- stage weights to LDS ----
    {
        const uint4* ws4 = (const uint4*)wsw;
        #pragma unroll
        for (int i = 0; i < 16; ++i) ((uint4*)sW12)[i*NTHR + tid] = ws4[i*NTHR + tid];
        #pragma unroll
        for (int i = 0; i < 4; ++i) {
            int c = i*NTHR + tid;
            if (c < 1792) {
                int f = c >> 6, nt = f/14, ks = f - nt*14;
                ((uint4*)sW3t)[c] = ws4[(W3OFF/16) + (nt*16+ks)*64 + (c & 63)];
            }
        }
        if (tid < 112) ((uint4*)sBias)[tid] = ws4[(BDOFF/16) + tid];
    }
    __syncthreads();    // only barrier

    const bool idx64 = __all(eli[2*lane + 1] == 0);
    const f16x8* w4g = (const f16x8*)(wsw + W4OFF/2);
    const f16x8 w4f0 = w4g[0*64+lane], w4f1 = w4g[1*64+lane],
                w4f2 = w4g[2*64+lane], w4f3 = w4g[3*64+lane];
    const f16x8* w3g = (const f16x8*)(wsw + W3OFF/2);
    const float4 b4lo = *(const float4*)b4;
    const float  b4e  = b4[4];

    const int gw = (blockIdx.x*NTHR + tid) >> 6;

    int t = gw, ru = 0, rb = 0;
    if (t < NT) {
        int e = t*32 + li;
        ru = idx64 ? eli[2*e]           : eli[e];
        rb = idx64 ? eli[2*(NEDGE + e)] : eli[NEDGE + e];
    }

    for (; t < NT; t += GW) {
        int tn = t + GW, run = 0, rbn = 0;
        if (tn < NT) {
            int e2 = tn*32 + li;
            run = idx64 ? eli[2*e2]           : eli[e2];
            rbn = idx64 ? eli[2*(NEDGE + e2)] : eli[NEDGE + e2];
        }

        // ---- layer 1: 16 k-steps vs LDS W1; acc init = bias ----
        f32x16 a0 = bias_init(sBias, 0, hi), a1 = bias_init(sBias, 1, hi);
        f32x16 a2 = bias_init(sBias, 2, hi), a3 = bias_init(sBias, 3, hi);
        #pragma unroll
        for (int ks = 0; ks < 16; ++ks) {
            f16x8 bz;
            if (EF16) {
                const f16* base = (ks < 8) ? (zu16 + (size_t)ru*128 + ks*16)
                                           : (zb16 + (size_t)rb*128 + (ks-8)*16);
                bz = *(const f16x8*)(base + hi*8);
            } else {
                const float* base = (ks < 8) ? (zu + (size_t)ru*128 + ks*16)
                                             : (zb + (size_t)rb*128 + (ks-8)*16);
                float4 va = *(const float4*)(base + hi*8);
                float4 vb = *(const float4*)(base + hi*8 + 4);
                union { unsigned int u[4]; f16x8 v; } z;
                z.u[0]=pkrne(va.x,va.y); z.u[1]=pkrne(va.z,va.w);
                z.u[2]=pkrne(vb.x,vb.y); z.u[3]=pkrne(vb.z,vb.w);
                bz = z.v;
            }
            a0 = MFMA(LD12(0*16 + ks), bz, a0);
            a1 = MFMA(LD12(1*16 + ks), bz, a1);
            a2 = MFMA(LD12(2*16 + ks), bz, a2);
            a3 = MFMA(LD12(3*16 + ks), bz, a3);
        }
        const f16x8 h1_0 = mkfrag<true,0>(a0), h1_1 = mkfrag<true,1>(a0);
        const f16x8 h1_2 = mkfrag<true,0>(a1), h1_3 = mkfrag<true,1>(a1);
        const f16x8 h1_4 = mkfrag<true,0>(a2), h1_5 = mkfrag<true,1>(a2);
        const f16x8 h1_6 = mkfrag<true,0>(a3), h1_7 = mkfrag<true,1>(a3);

        // ---- layer 2 (two halves) fused with layer-3 accumulation ----
        f32x16 c30 = bias_init(sBias, 12, hi), c31 = bias_init(sBias, 13, hi);
        #pragma unroll
        for (int h = 0; h < 2; ++h) {
            f32x16 b0 = bias_init(sBias, 4 + h*4 + 0, hi);
            f32x16 b1v = bias_init(sBias, 4 + h*4 + 1, hi);
            f32x16 b2v = bias_init(sBias, 4 + h*4 + 2, hi);
            f32x16 b3v = bias_init(sBias, 4 + h*4 + 3, hi);
            #pragma unroll
            for (int ks = 0; ks < 8; ++ks) {
                f16x8 bf = SEL8(ks, h1_0,h1_1,h1_2,h1_3,h1_4,h1_5,h1_6,h1_7);
                b0  = MFMA(LD12(64 + (h*4+0)*8 + ks), bf, b0);
                b1v = MFMA(LD12(64 + (h*4+1)*8 + ks), bf, b1v);
                b2v = MFMA(LD12(64 + (h*4+2)*8 + ks), bf, b2v);
                b3v = MFMA(LD12(64 + (h*4+3)*8 + ks), bf, b3v);
            }
            const f16x8 h2_0 = mkfrag<true,0>(b0),  h2_1 = mkfrag<true,1>(b0);
            const f16x8 h2_2 = mkfrag<true,0>(b1v), h2_3 = mkfrag<true,1>(b1v);
            const f16x8 h2_4 = mkfrag<true,0>(b2v), h2_5 = mkfrag<true,1>(b2v);
            const f16x8 h2_6 = mkfrag<true,0>(b3v), h2_7 = mkfrag<true,1>(b3v);
            #pragma unroll
            for (int ksl = 0; ksl < 8; ++ksl) {
                f16x8 bf2 = SEL8(ksl, h2_0,h2_1,h2_2,h2_3,h2_4,h2_5,h2_6,h2_7);
                int kk = h*8 + ksl;
                f16x8 a30 = (kk < 14) ? LDT3(0*14 + kk) : w3g[(0*16 + kk)*64 + lane];
                f16x8 a31 = (kk < 14) ? LDT3(1*14 + kk) : w3g[(1*16 + kk)*64 + lane];
                c30 = MFMA(a30, bf2, c30);
                c31 = MFMA(a31, bf2, c31);
            }
        }

        // ---- layer 3 epilogue -> layer 4 -> store ----
        const f16x8 h3_0 = mkfrag<true,0>(c30), h3_1 = mkfrag<true,1>(c30);
        const f16x8 h3_2 = mkfrag<true,0>(c31), h3_3 = mkfrag<true,1>(c31);

        f32x16 a4 = {};
        if (hi == 0) { a4[0]=b4lo.x; a4[1]=b4lo.y; a4[2]=b4lo.z; a4[3]=b4lo.w; }
        else         { a4[0]=b4e; }
        a4 = MFMA(w4f0, h3_0, a4);
        a4 = MFMA(w4f1, h3_1, a4);
        a4 = MFMA(w4f2, h3_2, a4);
        a4 = MFMA(w4f3, h3_3, a4);

        size_t eb = (size_t)(t*32 + li)*5;
        if (hi == 0) { out[eb+0]=a4[0]; out[eb+1]=a4[1]; out[eb+2]=a4[2]; out[eb+3]=a4[3]; }
        else         { out[eb+4]=a4[0]; }

        ru = run; rb = rbn;
    }
}

extern "C" void kernel_launch(void* const* d_in, const int* in_sizes, int n_in,
                              void* d_out, int out_size, void* d_ws, size_t ws_size,
                              hipStream_t stream) {
    const float* zu  = (const float*)d_in[0];
    const float* zb  = (const float*)d_in[1];
    const int*   eli = (const int*)d_in[2];
    const float* W1  = (const float*)d_in[3];
    const float* b1  = (const float*)d_in[4];
    const float* W2  = (const float*)d_in[5];
    const float* b2  = (const float*)d_in[6];
    const float* W3  = (const float*)d_in[7];
    const float* b3  = (const float*)d_in[8];
    const float* W4  = (const float*)d_in[9];
    const float* b4  = (const float*)d_in[10];
    float* out = (float*)d_out;

    f16* wsw  = (f16*)d_ws;
    f16* zu16 = (f16*)((char*)d_ws + ZUOFF);
    f16* zb16 = (f16*)((char*)d_ws + ZBOFF);

    wfrag_kernel<<<22, 512, 0, stream>>>(W1,b1,W2,b2,W3,b3,W4, (float*)d_ws);

    if (ws_size >= (size_t)WS_FULL) {
        ecvt_kernel<<<(2*(100000*128/8) + 511)/512, 512, 0, stream>>>(zu, zb, zu16, zb16);
        edge_mlp<true><<<GRID, NTHR, 0, stream>>>(eli, zu, zb, zu16, zb16, wsw, b4, out);
    } else {
        edge_mlp<false><<<GRID, NTHR, 0, stream>>>(eli, zu, zb, zu16, zb16, wsw, b4, out);
    }
}

// Round 6
// 203.105 us; speedup vs baseline: 8.5800x; 8.5800x over previous
//
#include <hip/hip_runtime.h>
#include <hip/hip_fp16.h>
#include <stdint.h>

typedef _Float16 f16;
typedef _Float16 f16x8 __attribute__((ext_vector_type(8)));
typedef float    f32x4v __attribute__((ext_vector_type(4)));
typedef float    f32x16 __attribute__((ext_vector_type(16)));

#define NEDGE 1000000
#define NT    31250        // 32-edge tiles (31250*32 = 1e6, exact)
#define NTHR  512
#define GRID  256
#define GW    (GRID*8)     // 2048 waves

// ---- d_ws layout (bytes); weight frags 1 KB each, sigma-row-permuted ----
#define W1OFF 0                 // 64 frags: f = nt*16+ks
#define W2OFF 65536             // 64 frags: f = nt*8+ks
#define W3OFF 131072            // 32 frags: f = nt*16+ks
#define W4OFF 163840            // 4 frags:  f = ks
#define BDOFF 167936            // biasD: 448 f32
#define ZUOFF 169984
#define ZBOFF (ZUOFF + 100000*128*2)
#define WS_FULL (ZBOFF + 100000*128*2)

// sigma: swap bits 2<->3 (involution). Verified R5 (absmax 7.8e-3).
__device__ __forceinline__ int sw23(int i) {
    return (i & 3) | ((i >> 1) & 4) | ((i << 1) & 8) | (i & 16);
}

// ---------------- weight fragment + biasD builder (verified R5) ----------------
__global__ __launch_bounds__(512) void wfrag_kernel(
    const float* __restrict__ W1, const float* __restrict__ b1,
    const float* __restrict__ W2, const float* __restrict__ b2,
    const float* __restrict__ W3, const float* __restrict__ b3,
    const float* __restrict__ W4, float* __restrict__ wsf)
{
    f16* ws = (f16*)wsf;
    const int NF = 164*64;
    int tid = blockIdx.x*512 + threadIdx.x;
    if (tid < NF) {
        int f = tid >> 6, lane = tid & 63;
        int li = lane & 31, hi = lane >> 5;
        int ip = sw23(li);
        f16 v[8];
        if (f < 64) {                       // W1 [128,256]
            int nt = f >> 4, ks = f & 15, n = nt*32 + ip;
            #pragma unroll
            for (int e = 0; e < 8; ++e) v[e] = (f16)W1[n*256 + ks*16 + hi*8 + e];
        } else if (f < 128) {               // W2 [256,128]
            int g = f-64, nt = g >> 3, ks = g & 7, n = nt*32 + ip;
            #pragma unroll
            for (int e = 0; e < 8; ++e) v[e] = (f16)W2[n*128 + ks*16 + hi*8 + e];
        } else if (f < 160) {               // W3 [64,256]
            int g = f-128, nt = g >> 4, ks = g & 15, n = nt*32 + ip;
            #pragma unroll
            for (int e = 0; e < 8; ++e) v[e] = (f16)W3[n*256 + ks*16 + hi*8 + e];
        } else {                            // W4 [5,64], rows >=5 zero, NO sigma
            int ks = f-160;
            #pragma unroll
            for (int e = 0; e < 8; ++e)
                v[e] = (li < 5) ? (f16)W4[li*64 + ks*16 + hi*8 + e] : (f16)0;
        }
        f16* d = ws + (size_t)f*512 + lane*8;
        #pragma unroll
        for (int e = 0; e < 8; ++e) d[e] = v[e];
    } else if (tid < NF + 448) {
        int j = tid - NF;
        int r = j & 15, hi = (j >> 4) & 1, nt = j >> 5;
        int n32 = (r & 7) + 8*hi + 16*(r >> 3);
        float bv = (nt < 4)  ? b1[nt*32 + n32]
                 : (nt < 12) ? b2[(nt-4)*32 + n32]
                             : b3[(nt-12)*32 + n32];
        *(float*)((char*)wsf + BDOFF + j*4) = bv;
    }
}

// ---------------- embedding f32 -> f16 ----------------
__device__ __forceinline__ void cvt8(const float* __restrict__ s, f16* __restrict__ d) {
    float4 a = ((const float4*)s)[0], b = ((const float4*)s)[1];
    union { f16 h[8]; uint4 u; } r;
    r.h[0]=(f16)a.x; r.h[1]=(f16)a.y; r.h[2]=(f16)a.z; r.h[3]=(f16)a.w;
    r.h[4]=(f16)b.x; r.h[5]=(f16)b.y; r.h[6]=(f16)b.z; r.h[7]=(f16)b.w;
    *(uint4*)d = r.u;
}
__global__ __launch_bounds__(512) void ecvt_kernel(
    const float* __restrict__ zu, const float* __restrict__ zb,
    f16* __restrict__ du, f16* __restrict__ db)
{
    const int NPER = 100000*128/8;
    int i = blockIdx.x*512 + threadIdx.x;
    if (i < NPER)          cvt8(zu + (size_t)i*8, du + (size_t)i*8);
    else if (i < 2*NPER) { int j = i - NPER; cvt8(zb + (size_t)j*8, db + (size_t)j*8); }
}

__device__ __forceinline__ unsigned int pkrne(float v0, float v1) {
    union { f16 h[2]; unsigned int u; } r;
    r.h[0] = (f16)v0; r.h[1] = (f16)v1; return r.u;
}

// lane-local epilogue (sigma makes this correct; verified R5)
template<bool RELU, int P>
__device__ __forceinline__ f16x8 mkfrag(f32x16 a) {
    float v0=a[8*P+0], v1=a[8*P+1], v2=a[8*P+2], v3=a[8*P+3];
    float v4=a[8*P+4], v5=a[8*P+5], v6=a[8*P+6], v7=a[8*P+7];
    if (RELU) {
        v0=fmaxf(v0,0.f); v1=fmaxf(v1,0.f); v2=fmaxf(v2,0.f); v3=fmaxf(v3,0.f);
        v4=fmaxf(v4,0.f); v5=fmaxf(v5,0.f); v6=fmaxf(v6,0.f); v7=fmaxf(v7,0.f);
    }
    union { unsigned int u[4]; f16x8 v; } fb;
    fb.u[0]=pkrne(v0,v1); fb.u[1]=pkrne(v2,v3); fb.u[2]=pkrne(v4,v5); fb.u[3]=pkrne(v6,v7);
    return fb.v;
}

__device__ __forceinline__ f32x16 bias_init(const float* sB, int nt14, int hi) {
    const f32x4v* p = (const f32x4v*)(sB + (nt14*2 + hi)*16);
    f32x4v q0=p[0], q1=p[1], q2=p[2], q3=p[3];
    f32x16 a;
    a[0]=q0[0];  a[1]=q0[1];  a[2]=q0[2];  a[3]=q0[3];
    a[4]=q1[0];  a[5]=q1[1];  a[6]=q1[2];  a[7]=q1[3];
    a[8]=q2[0];  a[9]=q2[1];  a[10]=q2[2]; a[11]=q2[3];
    a[12]=q3[0]; a[13]=q3[1]; a[14]=q3[2]; a[15]=q3[3];
    return a;
}

#define MFMA(A,B,C) __builtin_amdgcn_mfma_f32_32x32x16_f16((A),(B),(C),0,0,0)
#define SB() __builtin_amdgcn_sched_barrier(0)
#define LD12(f) (*(const f16x8*)(sW12 + ((f) << 9) + (lane << 3)))
#define LDT3(f) (*(const f16x8*)(sW3t + ((f) << 9) + (lane << 3)))
#define SEL8(k, v0,v1,v2,v3,v4,v5,v6,v7) \
    ((k)==0?(v0):(k)==1?(v1):(k)==2?(v2):(k)==3?(v3): \
     (k)==4?(v4):(k)==5?(v5):(k)==6?(v6):(v7))
#define ZSEL(k) ((k)==0?bz0:(k)==1?bz1:(k)==2?bz2:(k)==3?bz3:(k)==4?bz4:(k)==5?bz5: \
                 (k)==6?bz6:(k)==7?bz7:(k)==8?bz8:(k)==9?bz9:(k)==10?bz10:(k)==11?bz11: \
                 (k)==12?bz12:(k)==13?bz13:(k)==14?bz14:bz15)
// f32 fallback gather+convert of one 16-wide k-slice
#define CVTZ(basep, ksi) ({ \
    const float* bp_ = (basep) + (ksi)*16 + hi*8; \
    float4 va_ = *(const float4*)bp_; float4 vb_ = *(const float4*)(bp_+4); \
    union { unsigned int u[4]; f16x8 v; } z_; \
    z_.u[0]=pkrne(va_.x,va_.y); z_.u[1]=pkrne(va_.z,va_.w); \
    z_.u[2]=pkrne(vb_.x,vb_.y); z_.u[3]=pkrne(vb_.z,vb_.w); z_.v; })

// ---------------- fused streaming edge MLP ----------------
// Same dataflow as R5 (verified); new: sched_barrier(0) every 2 k-steps caps
// in-flight LDS loads (anti-spill), za gather in named SSA regs (live only
// during L1), W4 loaded at epilogue. No barriers in steady state.
template<bool EF16>
__global__ __launch_bounds__(NTHR, 2) void edge_mlp(
    const int* __restrict__ eli,
    const float* __restrict__ zu, const float* __restrict__ zb,
    const f16* __restrict__ zu16, const f16* __restrict__ zb16,
    const f16* __restrict__ wsw, const float* __restrict__ b4,
    float* __restrict__ out)
{
    __shared__ f16 sW12[128*512];    // 131072 B
    __shared__ f16 sW3t[28*512];     // 28672 B (W3 ks 0..13 per nt)
    __shared__ float sBias[448];     // 1792 B

    const int tid = threadIdx.x;
    const int lane = tid & 63;
    const int li = lane & 31;
    const int hi = lane >> 5;

    {
        const uint4* ws4 = (const uint4*)wsw;
        #pragma unroll
        for (int i = 0; i < 16; ++i) ((uint4*)sW12)[i*NTHR + tid] = ws4[i*NTHR + tid];
        #pragma unroll
        for (int i = 0; i < 4; ++i) {
            int c = i*NTHR + tid;
            if (c < 1792) {
                int f = c >> 6, nt = f/14, ks = f - nt*14;
                ((uint4*)sW3t)[c] = ws4[(W3OFF/16) + (nt*16+ks)*64 + (c & 63)];
            }
        }
        if (tid < 112) ((uint4*)sBias)[tid] = ws4[(BDOFF/16) + tid];
    }
    __syncthreads();    // only barrier

    const bool idx64 = __all(eli[2*lane + 1] == 0);
    const f16x8* w3g = (const f16x8*)(wsw + W3OFF/2);
    const f16x8* w4g = (const f16x8*)(wsw + W4OFF/2);
    const float4 b4lo = *(const float4*)b4;
    const float  b4e  = b4[4];

    const int gw = (blockIdx.x*NTHR + tid) >> 6;

    int t = gw, ru = 0, rb = 0;
    if (t < NT) {
        int e = t*32 + li;
        ru = idx64 ? eli[2*e]           : eli[e];
        rb = idx64 ? eli[2*(NEDGE + e)] : eli[NEDGE + e];
    }

    for (; t < NT; t += GW) {
        int tn = t + GW, run = 0, rbn = 0;
        if (tn < NT) {
            int e2 = tn*32 + li;
            run = idx64 ? eli[2*e2]           : eli[e2];
            rbn = idx64 ? eli[2*(NEDGE + e2)] : eli[NEDGE + e2];
        }

        // ---- gather current tile into named SSA regs (dead after L1) ----
        f16x8 bz0,bz1,bz2,bz3,bz4,bz5,bz6,bz7,bz8,bz9,bz10,bz11,bz12,bz13,bz14,bz15;
        if (EF16) {
            const f16x8* ur = (const f16x8*)(zu16 + (size_t)ru*128);
            const f16x8* br = (const f16x8*)(zb16 + (size_t)rb*128);
            bz0=ur[hi];     bz1=ur[2+hi];  bz2=ur[4+hi];  bz3=ur[6+hi];
            bz4=ur[8+hi];   bz5=ur[10+hi]; bz6=ur[12+hi]; bz7=ur[14+hi];
            bz8=br[hi];     bz9=br[2+hi];  bz10=br[4+hi]; bz11=br[6+hi];
            bz12=br[8+hi];  bz13=br[10+hi];bz14=br[12+hi];bz15=br[14+hi];
        } else {
            const float* ub = zu + (size_t)ru*128;
            const float* bb = zb + (size_t)rb*128;
            bz0=CVTZ(ub,0); bz1=CVTZ(ub,1); bz2=CVTZ(ub,2);  bz3=CVTZ(ub,3);
            bz4=CVTZ(ub,4); bz5=CVTZ(ub,5); bz6=CVTZ(ub,6);  bz7=CVTZ(ub,7);
            bz8=CVTZ(bb,0); bz9=CVTZ(bb,1); bz10=CVTZ(bb,2); bz11=CVTZ(bb,3);
            bz12=CVTZ(bb,4);bz13=CVTZ(bb,5);bz14=CVTZ(bb,6); bz15=CVTZ(bb,7);
        }

        // ---- layer 1: 16 k-steps vs LDS W1, pinned every 2 steps ----
        f32x16 a0 = bias_init(sBias, 0, hi), a1 = bias_init(sBias, 1, hi);
        f32x16 a2 = bias_init(sBias, 2, hi), a3 = bias_init(sBias, 3, hi);
        #pragma unroll
        for (int ks = 0; ks < 16; ++ks) {
            f16x8 bzk = ZSEL(ks);
            a0 = MFMA(LD12(0*16 + ks), bzk, a0);
            a1 = MFMA(LD12(1*16 + ks), bzk, a1);
            a2 = MFMA(LD12(2*16 + ks), bzk, a2);
            a3 = MFMA(LD12(3*16 + ks), bzk, a3);
            if (ks & 1) SB();
        }
        const f16x8 h1_0 = mkfrag<true,0>(a0), h1_1 = mkfrag<true,1>(a0);
        const f16x8 h1_2 = mkfrag<true,0>(a1), h1_3 = mkfrag<true,1>(a1);
        const f16x8 h1_4 = mkfrag<true,0>(a2), h1_5 = mkfrag<true,1>(a2);
        const f16x8 h1_6 = mkfrag<true,0>(a3), h1_7 = mkfrag<true,1>(a3);
        SB();

        // ---- layer 2 (two halves) fused with layer-3 accumulation ----
        f32x16 c30 = bias_init(sBias, 12, hi), c31 = bias_init(sBias, 13, hi);
        #pragma unroll
        for (int h = 0; h < 2; ++h) {
            f32x16 b0  = bias_init(sBias, 4 + h*4 + 0, hi);
            f32x16 b1v = bias_init(sBias, 4 + h*4 + 1, hi);
            f32x16 b2v = bias_init(sBias, 4 + h*4 + 2, hi);
            f32x16 b3v = bias_init(sBias, 4 + h*4 + 3, hi);
            #pragma unroll
            for (int ks = 0; ks < 8; ++ks) {
                f16x8 bf = SEL8(ks, h1_0,h1_1,h1_2,h1_3,h1_4,h1_5,h1_6,h1_7);
                b0  = MFMA(LD12(64 + (h*4+0)*8 + ks), bf, b0);
                b1v = MFMA(LD12(64 + (h*4+1)*8 + ks), bf, b1v);
                b2v = MFMA(LD12(64 + (h*4+2)*8 + ks), bf, b2v);
                b3v = MFMA(LD12(64 + (h*4+3)*8 + ks), bf, b3v);
                if (ks & 1) SB();
            }
            const f16x8 h2_0 = mkfrag<true,0>(b0),  h2_1 = mkfrag<true,1>(b0);
            const f16x8 h2_2 = mkfrag<true,0>(b1v), h2_3 = mkfrag<true,1>(b1v);
            const f16x8 h2_4 = mkfrag<true,0>(b2v), h2_5 = mkfrag<true,1>(b2v);
            const f16x8 h2_6 = mkfrag<true,0>(b3v), h2_7 = mkfrag<true,1>(b3v);
            SB();
            #pragma unroll
            for (int ksl = 0; ksl < 8; ++ksl) {
                f16x8 bf2 = SEL8(ksl, h2_0,h2_1,h2_2,h2_3,h2_4,h2_5,h2_6,h2_7);
                int kk = h*8 + ksl;
                f16x8 a30 = (kk < 14) ? LDT3(0*14 + kk) : w3g[(0*16 + kk)*64 + lane];
                f16x8 a31 = (kk < 14) ? LDT3(1*14 + kk) : w3g[(1*16 + kk)*64 + lane];
                c30 = MFMA(a30, bf2, c30);
                c31 = MFMA(a31, bf2, c31);
                if (ksl & 1) SB();
            }
        }

        // ---- layer 3 epilogue -> layer 4 -> store ----
        const f16x8 h3_0 = mkfrag<true,0>(c30), h3_1 = mkfrag<true,1>(c30);
        const f16x8 h3_2 = mkfrag<true,0>(c31), h3_3 = mkfrag<true,1>(c31);

        f32x16 a4 = {};
        if (hi == 0) { a4[0]=b4lo.x; a4[1]=b4lo.y; a4[2]=b4lo.z; a4[3]=b4lo.w; }
        else         { a4[0]=b4e; }
        a4 = MFMA(w4g[0*64+lane], h3_0, a4);
        a4 = MFMA(w4g[1*64+lane], h3_1, a4);
        a4 = MFMA(w4g[2*64+lane], h3_2, a4);
        a4 = MFMA(w4g[3*64+lane], h3_3, a4);

        size_t eb = (size_t)(t*32 + li)*5;
        if (hi == 0) { out[eb+0]=a4[0]; out[eb+1]=a4[1]; out[eb+2]=a4[2]; out[eb+3]=a4[3]; }
        else         { out[eb+4]=a4[0]; }

        ru = run; rb = rbn;
    }
}

extern "C" void kernel_launch(void* const* d_in, const int* in_sizes, int n_in,
                              void* d_out, int out_size, void* d_ws, size_t ws_size,
                              hipStream_t stream) {
    const float* zu  = (const float*)d_in[0];
    const float* zb  = (const float*)d_in[1];
    const int*   eli = (const int*)d_in[2];
    const float* W1  = (const float*)d_in[3];
    const float* b1  = (const float*)d_in[4];
    const float* W2  = (const float*)d_in[5];
    const float* b2  = (const float*)d_in[6];
    const float* W3  = (const float*)d_in[7];
    const float* b3  = (const float*)d_in[8];
    const float* W4  = (const float*)d_in[9];
    const float* b4  = (const float*)d_in[10];
    float* out = (float*)d_out;

    f16* wsw  = (f16*)d_ws;
    f16* zu16 = (f16*)((char*)d_ws + ZUOFF);
    f16* zb16 = (f16*)((char*)d_ws + ZBOFF);

    wfrag_kernel<<<22, 512, 0, stream>>>(W1,b1,W2,b2,W3,b3,W4, (float*)d_ws);

    if (ws_size >= (size_t)WS_FULL) {
        ecvt_kernel<<<(2*(100000*128/8) + 511)/512, 512, 0, stream>>>(zu, zb, zu16, zb16);
        edge_mlp<true><<<GRID, NTHR, 0, stream>>>(eli, zu, zb, zu16, zb16, wsw, b4, out);
    } else {
        edge_mlp<false><<<GRID, NTHR, 0, stream>>>(eli, zu, zb, zu16, zb16, wsw, b4, out);
    }
}